// Round 4
// baseline (198.511 us; speedup 1.0000x reference)
//
#include <hip/hip_runtime.h>
#include <stdint.h>

#define BATCH 8
#define HIN   28
#define CH    32
#define HO    14
#define NIN   784   // 28*28
#define NOUT  196   // 14*14

// One workgroup per (b, p) output window. Phases:
//  0. compute per-window argmax codes for ALL windows q of image b (each block
//     redundantly, mu reads are L2-hot: 100KB/image); build colmask[q][dj][half]
//     = 16-bit mask of channels whose code at window q equals dj. Own-p thread
//     also writes mu_out. (rowmask(r) == colmask[p][r] -- same definition.)
//  1. stream the 4 candidate input rows of Sigma as 16B chunks; chunk
//     (r, j, half, sub) is loaded iff some covered channel selects it
//     (sel = colmask[p][r][half] & colmask[q(j)][dj(j)][half], 4-bit slice).
//     Wave's 64 lanes cover a contiguous 1KB span with 16B-granular holes ->
//     near-streaming HBM pattern. Selected scalars scatter into LDS tile.
//  2. write the 25KB output tile fully coalesced.
// Every output element is written exactly once (unique (r,dj) per channel), so
// no tile init is needed. No workspace, no atomics, deterministic.
__global__ __launch_bounds__(256) void vdp_pool_fused_kernel(
        const float* __restrict__ mu_in,
        const float* __restrict__ sigma_in,
        float* __restrict__ mu_out,
        float* __restrict__ sigma_out)
{
    __shared__ float    out_tile[NOUT * CH];   // 25088 B
    __shared__ uint32_t colmask[NOUT * 8];     // 6272 B : [q][dj][half]

    const int blk = blockIdx.x;                // b*NOUT + p
    const int b   = blk / NOUT;
    const int p   = blk - b * NOUT;
    const int tid = threadIdx.x;

    // ---------------- Phase 0: window codes + masks (+ mu_out for own p) ----
    for (int w = tid; w < NOUT * 2; w += 256) {
        const int q2   = w >> 1;
        const int half = w & 1;
        const int qy = q2 / HO, qx = q2 - qy * HO;
        const float* base =
            mu_in + (((size_t)b * HIN + 2 * qy) * HIN + 2 * qx) * CH + half * 16;

        uint32_t kqh = 0;
        #pragma unroll
        for (int g = 0; g < 4; ++g) {
            const float4 v0 = *(const float4*)(base + g * 4);
            const float4 v1 = *(const float4*)(base + CH + g * 4);
            const float4 v2 = *(const float4*)(base + HIN * CH + g * 4);
            const float4 v3 = *(const float4*)(base + HIN * CH + CH + g * 4);
            float m0, m1, m2, m3;
            uint32_t k0, k1, k2, k3;
            { float best = v0.x; uint32_t k = 0;
              if (v1.x > best) { best = v1.x; k = 1; }
              if (v2.x > best) { best = v2.x; k = 2; }
              if (v3.x > best) { best = v3.x; k = 3; }
              m0 = best; k0 = k; }
            { float best = v0.y; uint32_t k = 0;
              if (v1.y > best) { best = v1.y; k = 1; }
              if (v2.y > best) { best = v2.y; k = 2; }
              if (v3.y > best) { best = v3.y; k = 3; }
              m1 = best; k1 = k; }
            { float best = v0.z; uint32_t k = 0;
              if (v1.z > best) { best = v1.z; k = 1; }
              if (v2.z > best) { best = v2.z; k = 2; }
              if (v3.z > best) { best = v3.z; k = 3; }
              m2 = best; k2 = k; }
            { float best = v0.w; uint32_t k = 0;
              if (v1.w > best) { best = v1.w; k = 1; }
              if (v2.w > best) { best = v2.w; k = 2; }
              if (v3.w > best) { best = v3.w; k = 3; }
              m3 = best; k3 = k; }
            kqh |= (k0 << (2 * (g * 4 + 0))) | (k1 << (2 * (g * 4 + 1))) |
                   (k2 << (2 * (g * 4 + 2))) | (k3 << (2 * (g * 4 + 3)));
            if (q2 == p) {
                *(float4*)(mu_out + (size_t)blk * CH + half * 16 + g * 4) =
                    make_float4(m0, m1, m2, m3);
            }
        }
        #pragma unroll
        for (int dj = 0; dj < 4; ++dj) {
            uint32_t m = 0;
            #pragma unroll
            for (int cl = 0; cl < 16; ++cl)
                m |= (((kqh >> (2 * cl)) & 3u) == (uint32_t)dj) ? (1u << cl) : 0u;
            colmask[q2 * 8 + dj * 2 + half] = m;
        }
    }
    __syncthreads();

    // ---------------- Phase 1: selective dense stream -> LDS scatter --------
    const float* sb = sigma_in + (size_t)b * NIN * NIN * CH;
    const int py = p / HO, px = p - py * HO;

    const int NITEM = 4 * NIN * 8;             // 25088 chunks of 16B
    for (int w = tid; w < NITEM; w += 256) {
        const int e    = w & 7;                // chunk within 128B row
        const int rj   = w >> 3;
        const int r    = rj / NIN;             // i-candidate (dy*2+dx)
        const int j    = rj - r * NIN;         // input flat col
        const int half = e >> 2;
        const int sub  = e & 3;

        const int jy = j / HIN, jx = j - jy * HIN;
        const int q  = (jy >> 1) * HO + (jx >> 1);
        const int dj = ((jy & 1) << 1) | (jx & 1);

        const uint32_t rmask = colmask[p * 8 + r * 2 + half];
        const uint32_t cmask = colmask[q * 8 + dj * 2 + half];
        const uint32_t sel4  = ((rmask & cmask) >> (sub * 4)) & 0xFu;
        if (sel4) {
            const int i = (2 * py + (r >> 1)) * HIN + 2 * px + (r & 1);
            const float4 v =
                *(const float4*)(sb + ((size_t)i * NIN + j) * CH + half * 16 + sub * 4);
            float* o = out_tile + q * CH + half * 16 + sub * 4;
            if (sel4 & 1u) o[0] = v.x;
            if (sel4 & 2u) o[1] = v.y;
            if (sel4 & 4u) o[2] = v.z;
            if (sel4 & 8u) o[3] = v.w;
        }
    }
    __syncthreads();

    // ---------------- Phase 2: coalesced tile write-out ---------------------
    {
        const float4* srcT = (const float4*)out_tile;
        float4* dstT = (float4*)(sigma_out + (size_t)blk * NOUT * CH);
        for (int w = tid; w < NOUT * CH / 4; w += 256)   // 1568 float4s
            dstT[w] = srcT[w];
    }
}

extern "C" void kernel_launch(void* const* d_in, const int* in_sizes, int n_in,
                              void* d_out, int out_size, void* d_ws, size_t ws_size,
                              hipStream_t stream) {
    const float* mu_in    = (const float*)d_in[0];
    const float* sigma_in = (const float*)d_in[1];

    float* mu_out    = (float*)d_out;                      // 8*14*14*32 floats
    float* sigma_out = (float*)d_out + BATCH * NOUT * CH;  // 8*196*196*32 floats

    vdp_pool_fused_kernel<<<BATCH * NOUT, 256, 0, stream>>>(
        mu_in, sigma_in, mu_out, sigma_out);
}

// Round 5
// 144.889 us; speedup vs baseline: 1.3701x; 1.3701x over previous
//
#include <hip/hip_runtime.h>
#include <stdint.h>

#define BATCH 8
#define HIN   28
#define CH    32
#define HO    14
#define NIN   784   // 28*28
#define NOUT  196   // 14*14

#define NITEM  (4 * NIN * 8)      // 25088 16B-lane-items per block
#define ITERS  (NITEM / 256)      // 98
#define UNROLL 7
#define OUTER  (ITERS / UNROLL)   // 14

// One workgroup per (b, p). Phase 0: per-window argmax codes for all windows
// of image b (redundant per block, L2-hot) -> colmask[q][dj][half] (16-bit
// channel masks); own-p threads write mu_out. Phase 1: stream the block's 4
// candidate Sigma rows as 16B/lane chunks, manually unrolled x7 so 7 float4
// loads are in flight per wave (predicated-off lanes redirect to a dummy base
// address instead of branching -> single basic block, load cluster intact,
// HBM fetch stays selective at 64B granularity). Selected scalars scatter to
// the LDS tile. Phase 2: 25KB tile streamed out fully coalesced.
// Each output word is written exactly once (unique (r,dj) per channel) -> no
// tile init, no atomics, deterministic.
__global__ __launch_bounds__(256, 5) void vdp_pool_fused_kernel(
        const float* __restrict__ mu_in,
        const float* __restrict__ sigma_in,
        float* __restrict__ mu_out,
        float* __restrict__ sigma_out)
{
    __shared__ float    out_tile[NOUT * CH];   // 25088 B
    __shared__ uint32_t colmask[NOUT * 8];     // 6272 B : [q][dj][half]

    const int blk = blockIdx.x;                // b*NOUT + p
    const int b   = blk / NOUT;
    const int p   = blk - b * NOUT;
    const int tid = threadIdx.x;

    // ---------------- Phase 0: window codes + masks (+ mu_out for own p) ----
    for (int w = tid; w < NOUT * 2; w += 256) {
        const int q2   = w >> 1;
        const int half = w & 1;
        const int qy = q2 / HO, qx = q2 - qy * HO;
        const float* base =
            mu_in + (((size_t)b * HIN + 2 * qy) * HIN + 2 * qx) * CH + half * 16;

        uint32_t kqh = 0;
        #pragma unroll
        for (int g = 0; g < 4; ++g) {
            const float4 v0 = *(const float4*)(base + g * 4);
            const float4 v1 = *(const float4*)(base + CH + g * 4);
            const float4 v2 = *(const float4*)(base + HIN * CH + g * 4);
            const float4 v3 = *(const float4*)(base + HIN * CH + CH + g * 4);
            float m0, m1, m2, m3;
            uint32_t k0, k1, k2, k3;
            { float best = v0.x; uint32_t k = 0;
              if (v1.x > best) { best = v1.x; k = 1; }
              if (v2.x > best) { best = v2.x; k = 2; }
              if (v3.x > best) { best = v3.x; k = 3; }
              m0 = best; k0 = k; }
            { float best = v0.y; uint32_t k = 0;
              if (v1.y > best) { best = v1.y; k = 1; }
              if (v2.y > best) { best = v2.y; k = 2; }
              if (v3.y > best) { best = v3.y; k = 3; }
              m1 = best; k1 = k; }
            { float best = v0.z; uint32_t k = 0;
              if (v1.z > best) { best = v1.z; k = 1; }
              if (v2.z > best) { best = v2.z; k = 2; }
              if (v3.z > best) { best = v3.z; k = 3; }
              m2 = best; k2 = k; }
            { float best = v0.w; uint32_t k = 0;
              if (v1.w > best) { best = v1.w; k = 1; }
              if (v2.w > best) { best = v2.w; k = 2; }
              if (v3.w > best) { best = v3.w; k = 3; }
              m3 = best; k3 = k; }
            kqh |= (k0 << (2 * (g * 4 + 0))) | (k1 << (2 * (g * 4 + 1))) |
                   (k2 << (2 * (g * 4 + 2))) | (k3 << (2 * (g * 4 + 3)));
            if (q2 == p) {
                *(float4*)(mu_out + (size_t)blk * CH + half * 16 + g * 4) =
                    make_float4(m0, m1, m2, m3);
            }
        }
        #pragma unroll
        for (int dj = 0; dj < 4; ++dj) {
            uint32_t m = 0;
            #pragma unroll
            for (int cl = 0; cl < 16; ++cl)
                m |= (((kqh >> (2 * cl)) & 3u) == (uint32_t)dj) ? (1u << cl) : 0u;
            colmask[q2 * 8 + dj * 2 + half] = m;
        }
    }
    __syncthreads();

    // ---------------- Phase 1: selective stream, 7-deep MLP, LDS scatter ----
    const float* sb = sigma_in + (size_t)b * NIN * NIN * CH;
    const int py = p / HO, px = p - py * HO;
    const uint32_t ibase = (uint32_t)(2 * py) * HIN + 2 * px;
    const uint32_t pbase = (uint32_t)p * 8u;

    for (int o = 0; o < OUTER; ++o) {
        float4   val[UNROLL];
        uint32_t off[UNROLL];
        uint32_t selpack = 0;
        #pragma unroll
        for (int u = 0; u < UNROLL; ++u) {
            const uint32_t w    = (uint32_t)tid + (uint32_t)(o * UNROLL + u) * 256u;
            const uint32_t sub  = w & 3u;
            const uint32_t g    = w >> 2;          // (r*NIN + j)*2 + half
            const uint32_t half = g & 1u;
            const uint32_t rj   = g >> 1;
            const uint32_t r    = rj / NIN;        // i-candidate (dy*2+dx)
            const uint32_t j    = rj - r * NIN;
            const uint32_t jy   = j / HIN, jx = j - jy * HIN;
            const uint32_t q    = (jy >> 1) * HO + (jx >> 1);
            const uint32_t dj   = ((jy & 1u) << 1) | (jx & 1u);

            const uint32_t rmask = colmask[pbase + r * 2u + half];
            const uint32_t cmask = colmask[q * 8u + dj * 2u + half];
            const uint32_t sel16 = rmask & cmask;
            selpack |= ((sel16 >> (sub * 4u)) & 0xFu) << (u * 4);

            const uint32_t i = ibase + (r >> 1) * HIN + (r & 1u);
            const float* addr = sb + ((size_t)i * NIN + j) * CH + half * 16u + sub * 4u;
            const float* asel = sel16 ? addr : sb;   // dummy base keeps cluster
            val[u] = *(const float4*)asel;
            off[u] = q * CH + half * 16u + sub * 4u;
        }
        #pragma unroll
        for (int u = 0; u < UNROLL; ++u) {
            const uint32_t s4 = (selpack >> (u * 4)) & 0xFu;
            if (s4 & 1u) out_tile[off[u] + 0] = val[u].x;
            if (s4 & 2u) out_tile[off[u] + 1] = val[u].y;
            if (s4 & 4u) out_tile[off[u] + 2] = val[u].z;
            if (s4 & 8u) out_tile[off[u] + 3] = val[u].w;
        }
    }
    __syncthreads();

    // ---------------- Phase 2: coalesced tile write-out ---------------------
    {
        const float4* srcT = (const float4*)out_tile;
        float4* dstT = (float4*)(sigma_out + (size_t)blk * NOUT * CH);
        #pragma unroll
        for (int w = tid; w < NOUT * CH / 4; w += 256)   // 1568 float4s
            dstT[w] = srcT[w];
    }
}

extern "C" void kernel_launch(void* const* d_in, const int* in_sizes, int n_in,
                              void* d_out, int out_size, void* d_ws, size_t ws_size,
                              hipStream_t stream) {
    const float* mu_in    = (const float*)d_in[0];
    const float* sigma_in = (const float*)d_in[1];

    float* mu_out    = (float*)d_out;                      // 8*14*14*32 floats
    float* sigma_out = (float*)d_out + BATCH * NOUT * CH;  // 8*196*196*32 floats

    vdp_pool_fused_kernel<<<BATCH * NOUT, 256, 0, stream>>>(
        mu_in, sigma_in, mu_out, sigma_out);
}

// Round 6
// 134.972 us; speedup vs baseline: 1.4708x; 1.0735x over previous
//
#include <hip/hip_runtime.h>
#include <stdint.h>

#define BATCH 8
#define HIN   28
#define CH    32
#define HO    14
#define NIN   784   // 28*28
#define NOUT  196   // 14*14

#define NITEM  (4 * NIN * 8)      // 25088 16B-items per block
#define ITERS  (NITEM / 256)      // 98 per thread
#define UNROLL 7
#define OUTER  (ITERS / UNROLL)   // 14
#define TILE_W (NOUT * CH)        // 6272 words

typedef float f32x4 __attribute__((ext_vector_type(4)));

// One workgroup per (b, p).
// Phase 0: per-window argmax codes for all windows of image b (L2-hot mu) ->
//          colmask[q][dj][half]; own-p threads write mu_out.
// Phase 0.5: fold (q,dj) lookup into one table: cmq[j][half] =
//          (q*CH)<<16 | cmask16 ; pack this block's 4 row-masks in a u64 reg.
// Phase 1: FULLY DENSE stream of the block's 4 candidate Sigma rows
//          (4 x 100KB contiguous, each global line read exactly once).
//          Load addresses are pure functions of the counter (no mask
//          dependence) -> deep pipelining; 7 loads in flight explicitly.
//          Branchless LDS scatter: per float one cndmask picks the real
//          tile slot or a per-lane trash slot.
// Phase 2: 25KB tile -> global, fully coalesced, nontemporal.
// Each output word is written exactly once by construction (unique (r,dj)
// per channel): no init, no atomics, deterministic.
__global__ __launch_bounds__(256, 4) void vdp_pool_fused_kernel(
        const float* __restrict__ mu_in,
        const float* __restrict__ sigma_in,
        float* __restrict__ mu_out,
        float* __restrict__ sigma_out)
{
    __shared__ __align__(16) float out_tile[TILE_W + 64];  // +64 trash words
    __shared__ uint32_t colmask[NOUT * 8];                 // [q][dj][half]
    __shared__ uint32_t cmq[NIN * 2];                      // [j][half]

    const int blk = blockIdx.x;                // b*NOUT + p
    const int b   = blk / NOUT;
    const int p   = blk - b * NOUT;
    const int tid = threadIdx.x;

    // ---------------- Phase 0: window codes + masks (+ mu_out for own p) ----
    for (int w = tid; w < NOUT * 2; w += 256) {
        const int q2   = w >> 1;
        const int half = w & 1;
        const int qy = q2 / HO, qx = q2 - qy * HO;
        const float* base =
            mu_in + (((size_t)b * HIN + 2 * qy) * HIN + 2 * qx) * CH + half * 16;

        uint32_t kqh = 0;
        #pragma unroll
        for (int g = 0; g < 4; ++g) {
            const float4 v0 = *(const float4*)(base + g * 4);
            const float4 v1 = *(const float4*)(base + CH + g * 4);
            const float4 v2 = *(const float4*)(base + HIN * CH + g * 4);
            const float4 v3 = *(const float4*)(base + HIN * CH + CH + g * 4);
            float m0, m1, m2, m3;
            uint32_t k0, k1, k2, k3;
            { float best = v0.x; uint32_t k = 0;
              if (v1.x > best) { best = v1.x; k = 1; }
              if (v2.x > best) { best = v2.x; k = 2; }
              if (v3.x > best) { best = v3.x; k = 3; }
              m0 = best; k0 = k; }
            { float best = v0.y; uint32_t k = 0;
              if (v1.y > best) { best = v1.y; k = 1; }
              if (v2.y > best) { best = v2.y; k = 2; }
              if (v3.y > best) { best = v3.y; k = 3; }
              m1 = best; k1 = k; }
            { float best = v0.z; uint32_t k = 0;
              if (v1.z > best) { best = v1.z; k = 1; }
              if (v2.z > best) { best = v2.z; k = 2; }
              if (v3.z > best) { best = v3.z; k = 3; }
              m2 = best; k2 = k; }
            { float best = v0.w; uint32_t k = 0;
              if (v1.w > best) { best = v1.w; k = 1; }
              if (v2.w > best) { best = v2.w; k = 2; }
              if (v3.w > best) { best = v3.w; k = 3; }
              m3 = best; k3 = k; }
            kqh |= (k0 << (2 * (g * 4 + 0))) | (k1 << (2 * (g * 4 + 1))) |
                   (k2 << (2 * (g * 4 + 2))) | (k3 << (2 * (g * 4 + 3)));
            if (q2 == p) {
                *(float4*)(mu_out + (size_t)blk * CH + half * 16 + g * 4) =
                    make_float4(m0, m1, m2, m3);
            }
        }
        #pragma unroll
        for (int dj = 0; dj < 4; ++dj) {
            uint32_t m = 0;
            #pragma unroll
            for (int cl = 0; cl < 16; ++cl)
                m |= (((kqh >> (2 * cl)) & 3u) == (uint32_t)dj) ? (1u << cl) : 0u;
            colmask[q2 * 8 + dj * 2 + half] = m;
        }
    }
    __syncthreads();

    // ---------------- Phase 0.5: fold tables ------------------------------
    for (int j = tid; j < NIN; j += 256) {
        const int jy = j / HIN, jx = j - jy * HIN;
        const int q  = (jy >> 1) * HO + (jx >> 1);
        const int dj = ((jy & 1) << 1) | (jx & 1);
        const uint32_t qb = (uint32_t)(q * CH) << 16;
        cmq[j * 2 + 0] = qb | colmask[q * 8 + dj * 2 + 0];
        cmq[j * 2 + 1] = qb | colmask[q * 8 + dj * 2 + 1];
    }
    const uint32_t half = ((uint32_t)tid >> 2) & 1u;   // constant per thread
    const uint32_t shs  = ((uint32_t)tid & 3u) * 4u;   // sub*4, constant
    const uint32_t hs   = half * 16u + shs;
    unsigned long long rmpack = 0ull;                  // 4 x 16-bit row masks
    #pragma unroll
    for (int r = 0; r < 4; ++r)
        rmpack |= (unsigned long long)(colmask[p * 8 + r * 2 + (int)half] & 0xFFFFu)
                  << (16 * r);
    __syncthreads();

    // ---------------- Phase 1: dense stream + branchless LDS scatter -------
    const float* sb = sigma_in + (size_t)b * NIN * NIN * CH;
    const int py = p / HO, px = p - py * HO;
    const uint32_t ibase = (uint32_t)(2 * py) * HIN + 2u * px;
    const uint32_t rjb   = (uint32_t)tid >> 3;         // 8 lanes per (r,j) row
    const uint32_t trash = TILE_W + ((uint32_t)tid & 63u);

    for (int o = 0; o < OUTER; ++o) {
        f32x4    val[UNROLL];
        uint32_t tab[UNROLL];
        uint32_t rmv[UNROLL];
        #pragma unroll
        for (int u = 0; u < UNROLL; ++u) {
            const uint32_t rj = rjb + (uint32_t)(o * UNROLL + u) * 32u;
            const uint32_t r  = rj / NIN;              // magic-mul
            const uint32_t j  = rj - r * NIN;
            const uint32_t i  = ibase + (r >> 1) * HIN + (r & 1u);
            val[u] = __builtin_nontemporal_load(
                (const f32x4*)(sb + (((size_t)i * NIN + j) << 5) + hs));
            tab[u] = cmq[j * 2 + half];
            rmv[u] = (uint32_t)(rmpack >> (r * 16u)) & 0xFFFFu;
        }
        #pragma unroll
        for (int u = 0; u < UNROLL; ++u) {
            const uint32_t sel16 = rmv[u] & (tab[u] & 0xFFFFu);
            const uint32_t s4    = (sel16 >> shs) & 0xFu;
            const uint32_t base  = (tab[u] >> 16) + hs;
            out_tile[(s4 & 1u) ? base + 0u : trash] = val[u][0];
            out_tile[(s4 & 2u) ? base + 1u : trash] = val[u][1];
            out_tile[(s4 & 4u) ? base + 2u : trash] = val[u][2];
            out_tile[(s4 & 8u) ? base + 3u : trash] = val[u][3];
        }
    }
    __syncthreads();

    // ---------------- Phase 2: coalesced nontemporal tile write-out --------
    {
        const f32x4* srcT = (const f32x4*)out_tile;
        f32x4* dstT = (f32x4*)(sigma_out + (size_t)blk * TILE_W);
        for (int w = tid; w < TILE_W / 4; w += 256)    // 1568 f32x4
            __builtin_nontemporal_store(srcT[w], &dstT[w]);
    }
}

extern "C" void kernel_launch(void* const* d_in, const int* in_sizes, int n_in,
                              void* d_out, int out_size, void* d_ws, size_t ws_size,
                              hipStream_t stream) {
    const float* mu_in    = (const float*)d_in[0];
    const float* sigma_in = (const float*)d_in[1];

    float* mu_out    = (float*)d_out;                      // 8*14*14*32 floats
    float* sigma_out = (float*)d_out + BATCH * NOUT * CH;  // 8*196*196*32 floats

    vdp_pool_fused_kernel<<<BATCH * NOUT, 256, 0, stream>>>(
        mu_in, sigma_in, mu_out, sigma_out);
}